// Round 13
// baseline (2808.294 us; speedup 1.0000x reference)
//
#include <hip/hip_runtime.h>
#include <hip/hip_bf16.h>

// GRU forward: B=64, T=512, I=512, U=512, out [B,T,U] fp32.
// Round 13 = round 12 + two isolated changes:
//  (1) scan: SOFTWARE-PIPELINED POLLING. The r12 spin was issue-8-loads ->
//      vmcnt(0) -> tag-check -> repeat (poll period ~= 1 L3 RT; detect lag
//      ~1.5 RT after visibility). Now two 8-load batches alternate in flight:
//      check batch A while batch B flies -> detect lag ~1.25 RT. Tag-in-u64
//      means any batch with matching tags is valid regardless of issue time.
//      Unpack duplicated per winner (no runtime-indexed register arrays).
//  (2) xgemm: 4 row-tiles per wave (block = 64 rows x 512 cols, 8 waves,
//      grid 1536, LB(512,1)). Each B-frag load feeds 12 MFMAs; weight
//      traffic halves again (3 -> 1.5 GB; r11 measured ~97us/GB).
// Protocol recap (r9/r10): gates store h as one atomic u64 {hi0,hi1,lo0,lo1}
// with 2-bit tag (t%3)+1 in the two lo-bf16 LSBs (err<=2^-16), fire-and-
// forget; consumers spin on their 8 slots until tags match -> detect IS the
// load. hsh parity-double-buffered; 2 raw barriers/step (lgkmcnt only).
// __launch_bounds__(512,1) so the scan R-slice stays register-resident.

typedef float f32x4 __attribute__((ext_vector_type(4)));
typedef float f32x2 __attribute__((ext_vector_type(2)));
typedef short bf16x8 __attribute__((ext_vector_type(8)));
typedef unsigned long long u64;
typedef unsigned int u32;
typedef unsigned short u16;
typedef u32 u32x4 __attribute__((ext_vector_type(4)));

#define MFMA16(a, b, c) __builtin_amdgcn_mfma_f32_16x16x32_bf16((a), (b), (c), 0, 0, 0)

__device__ __forceinline__ float bf2f(__hip_bfloat16 v) { return __bfloat162float(v); }

__device__ __forceinline__ void split_bf(float v, short& hi, short& lo) {
    __hip_bfloat16 h = __float2bfloat16(v);
    float rem = v - __bfloat162float(h);
    __hip_bfloat16 l = __float2bfloat16(rem);
    hi = __builtin_bit_cast(short, h);
    lo = __builtin_bit_cast(short, l);
}

// Raw barrier: LDS-drain only. No vmcnt drain (that's the point).
__device__ __forceinline__ void wg_barrier() {
    __builtin_amdgcn_sched_barrier(0);
    asm volatile("s_waitcnt lgkmcnt(0)" ::: "memory");
    __builtin_amdgcn_s_barrier();
    __builtin_amdgcn_sched_barrier(0);
}

// ---------------------------------------------------------------- zero scratch
__global__ void zero_kernel(float* p, int n) {
    int i = blockIdx.x * blockDim.x + threadIdx.x;
    int stride = gridDim.x * blockDim.x;
    for (; i < n; i += stride) p[i] = 0.f;
}

// ------------------------------------------------- pack weights into B-frags
// Source W [512 x 1536] fp32. Frag (tile,kk): lane l element e =
// W[kk*32 + 8*(l>>4) + e][tile*16 + (l&15)], stored hi/lo bf16 planes.
__global__ __launch_bounds__(64, 1) void pack_w_kernel(const float* __restrict__ W,
                                                       short* __restrict__ dhi,
                                                       short* __restrict__ dlo) {
    int bid = blockIdx.x;   // tile*16 + kk, 0..1535
    int lane = threadIdx.x; // 0..63
    int col = (bid >> 4) * 16 + (lane & 15);
    int kbase = (bid & 15) * 32 + (lane >> 4) * 8;
    bf16x8 vh, vl;
#pragma unroll
    for (int e = 0; e < 8; e++) {
        float v = W[(kbase + e) * 1536 + col];
        short h, l;
        split_bf(v, h, l);
        vh[e] = h;
        vl[e] = l;
    }
    *(bf16x8*)(dhi + bid * 512 + lane * 8) = vh;
    *(bf16x8*)(dlo + bid * 512 + lane * 8) = vl;
}

// ------------------------------------------------------------- x_all GEMM
// 1536 blocks = 512 row-blocks (64 rows) x 3 col-groups, 512 threads.
// Wave handles col-tiles cg*32 + wave*4..+3 for ALL 4 row-tiles: each B-frag
// load feeds 12 MFMAs (4 rows x 3 hi/lo passes); weights read once per block.
__global__ __launch_bounds__(512, 1) void xgemm_kernel(
    const float* __restrict__ A, const short* __restrict__ wkh,
    const short* __restrict__ wkl, const float* __restrict__ bias,
    __hip_bfloat16* __restrict__ xhi, __hip_bfloat16* __restrict__ xlo, int xlo_en) {
    int bid = blockIdx.x; // 0..1535
    int cg = bid % 3;
    int rb = bid / 3; // rows rb*64 .. +63
    int wave = threadIdx.x >> 6, lane = threadIdx.x & 63;
    int arow0 = rb * 64 + (lane & 15);
    const float* ab = A + (size_t)arow0 * 512 + (lane >> 4) * 8;

    f32x4 acc[4][4]; // [row-tile][col-tile]
#pragma unroll
    for (int rt = 0; rt < 4; rt++)
#pragma unroll
        for (int j = 0; j < 4; j++) acc[rt][j] = (f32x4){0.f, 0.f, 0.f, 0.f};

#pragma unroll 1
    for (int kk = 0; kk < 16; kk++) {
        bf16x8 ah[4], al[4];
#pragma unroll
        for (int rt = 0; rt < 4; rt++) {
            f32x4 a0 = *(const f32x4*)(ab + (size_t)rt * 16 * 512 + kk * 32);
            f32x4 a1 = *(const f32x4*)(ab + (size_t)rt * 16 * 512 + kk * 32 + 4);
#pragma unroll
            for (int e = 0; e < 8; e++) {
                float v = (e < 4) ? a0[e] : a1[e - 4];
                short h, l;
                split_bf(v, h, l);
                ah[rt][e] = h;
                al[rt][e] = l;
            }
        }
#pragma unroll
        for (int j = 0; j < 4; j++) {
            int frag = (cg * 32 + wave * 4 + j) * 16 + kk;
            bf16x8 bh = *(const bf16x8*)(wkh + (size_t)frag * 512 + lane * 8);
            bf16x8 bl = *(const bf16x8*)(wkl + (size_t)frag * 512 + lane * 8);
#pragma unroll
            for (int rt = 0; rt < 4; rt++) {
                acc[rt][j] = MFMA16(ah[rt], bh, acc[rt][j]);
                acc[rt][j] = MFMA16(al[rt], bh, acc[rt][j]);
                acc[rt][j] = MFMA16(ah[rt], bl, acc[rt][j]);
            }
        }
    }
    int colin = lane & 15, r4 = (lane >> 4) * 4;
#pragma unroll
    for (int j = 0; j < 4; j++) {
        int colg = (cg * 32 + wave * 4 + j) * 16 + colin;
        float bv = bias[colg];
#pragma unroll
        for (int rt = 0; rt < 4; rt++) {
#pragma unroll
            for (int r = 0; r < 4; r++) {
                float v = acc[rt][j][r] + bv;
                int rowg = rb * 64 + rt * 16 + r4 + r;
                short h, l;
                split_bf(v, h, l);
                xhi[(size_t)rowg * 1536 + colg] = __builtin_bit_cast(__hip_bfloat16, h);
                if (xlo_en)
                    xlo[(size_t)rowg * 1536 + colg] =
                        __builtin_bit_cast(__hip_bfloat16, l);
            }
        }
    }
}

// ------------------------------------------------------------------ scan
// hbuf2 layout: [par(2)][group(4)][4096 u64]; slot s within a group:
// chunk=s>>8 (peer WG w), lane'=(s>>2)&63, epair=s&3. u64 = {hi0,hi1,lo0,lo1}
// for (row=lane'&15, units 32*chunk + 8*(lane'>>4) + 2*epair..+1), tag bits
// in lo0/lo1 LSBs. hsh u32 view: hshu[par*8192 + plane*4096 + s].
__global__ __launch_bounds__(512, 1) void scan_kernel(
    const __hip_bfloat16* __restrict__ xhi, const __hip_bfloat16* __restrict__ xlo,
    const short* __restrict__ wrh, const short* __restrict__ wrl,
    const float* __restrict__ bias, float* __restrict__ out,
    u64* hbuf2, int xlo_en) {
    const int bid = blockIdx.x;
    const int g = bid & 3;
    const int w = bid >> 2;
    const int tid = threadIdx.x;
    const int wave = tid >> 6;
    const int lane = tid & 63;

    __shared__ __align__(16) float pre[6][16][16];
    __shared__ __align__(16) __hip_bfloat16 xsh[2][2][16][104]; // [par][plane]
    __shared__ __align__(16) __hip_bfloat16 hsh[2][2][16][512]; // [par][plane][kk][frag]
    __shared__ float rb[96];

    if (tid < 96) rb[tid] = bias[1536 + (tid >> 5) * 512 + w * 32 + (tid & 31)];

    // persistent B fragments (hi+lo) for waves 0-5 (LB(512,1): stays resident)
    bf16x8 bh[16], bl[16];
    if (wave < 6) {
        int tile = (wave >> 1) * 32 + 2 * w + (wave & 1);
#pragma unroll
        for (int kk = 0; kk < 16; kk++) {
            bh[kk] = *(const bf16x8*)(wrh + (tile * 16 + kk) * 512 + lane * 8);
            bl[kk] = *(const bf16x8*)(wrl + (tile * 16 + kk) * 512 + lane * 8);
        }
#pragma unroll
        for (int kk = 0; kk < 16; kk++) {
            asm volatile("" : "+v"(bh[kk]), "+v"(bl[kk])); // defeat remat
        }
    } else {
        // x[0] prefetch straight into xsh[0]
        int it0 = tid - 384; // 0..127
        int nch = xlo_en ? 384 : 192;
        for (int c = it0; c < nch; c += 128) {
            int plane = c / 192, rem = c % 192;
            int row_ = rem / 12, cw = rem % 12;
            const __hip_bfloat16* src = (plane ? xlo : xhi) +
                                        (size_t)((g * 16 + row_) * 512) * 1536 +
                                        (cw >> 2) * 512 + w * 32 + (cw & 3) * 8;
            *(bf16x8*)&xsh[0][plane][row_][(cw >> 2) * 32 + (cw & 3) * 8] =
                *(const bf16x8*)src;
        }
    }

    const int grow = tid & 15; // gate thread: batch row
    const int q = tid >> 4;    // gate thread: unit pair 0..15 (tid<256)
    float h0 = 0.f, h1 = 0.f;
    const int hslot = w * 256 + (grow + 16 * (q >> 2)) * 4 + (q & 3);
    const int sA = tid * 4;        // staging slots [sA, sA+4)
    const int sB = 2048 + tid * 4; // staging slots [sB, sB+4)
    const int xit = tid - 384;     // x-prefetch thread index (waves 6-7)

    u32* hshu = (u32*)hsh;

    __syncthreads();

    for (int t = 0; t < 512; t++) {
        const int par = t & 1;
        // ================= A1: pipelined tag-validated h load ===============
        const u64* gb = hbuf2 + ((size_t)(((t - 1) & 1) * 4 + g)) * 4096;

        // unpack helper: writes one 8-u64 batch into hsh[par] (16B-stride b128)
        u32* hp = hshu + par * 8192;
        auto unpack8 = [&](const u64* sv) __attribute__((always_inline)) {
            u32x4 a0, a1, b0, b1;
#pragma unroll
            for (int j = 0; j < 4; j++) {
                a0[j] = (u32)sv[j];
                b0[j] = (u32)(sv[j] >> 32);
                a1[j] = (u32)sv[4 + j];
                b1[j] = (u32)(sv[4 + j] >> 32);
            }
            *(u32x4*)&hp[sA] = a0;
            *(u32x4*)&hp[sB] = a1;
            *(u32x4*)&hp[4096 + sA] = b0;
            *(u32x4*)&hp[4096 + sB] = b1;
        };

        u64 sva[8], svb[8];
#define LOAD8(dst)                                                                   \
    do {                                                                             \
        _Pragma("unroll") for (int j = 0; j < 4; j++) dst[j] =                       \
            __hip_atomic_load(gb + sA + j, __ATOMIC_RELAXED,                         \
                              __HIP_MEMORY_SCOPE_AGENT);                             \
        _Pragma("unroll") for (int j = 0; j < 4; j++) dst[4 + j] =                   \
            __hip_atomic_load(gb + sB + j, __ATOMIC_RELAXED,                         \
                              __HIP_MEMORY_SCOPE_AGENT);                             \
    } while (0)

        if (t == 0) {
            LOAD8(sva);
            unpack8(sva);
        } else {
            const int expv = ((t - 1) % 3) + 1;
            const u64 expm = ((u64)(expv & 1) << 32) | ((u64)((expv >> 1) & 1) << 48);
            const u64 TAGM = (1ULL << 32) | (1ULL << 48);
            LOAD8(sva);
            long spins = 0;
            int winner = 0; // 0 = sva, 1 = svb
            while (true) {
                if (winner == 0) {
                    LOAD8(svb); // B in flight while we wait+check A
                    u64 diff = 0;
#pragma unroll
                    for (int j = 0; j < 8; j++) diff |= (sva[j] ^ expm) & TAGM;
                    if (diff == 0) break;
                    winner = 1;
                } else {
                    LOAD8(sva); // A in flight while we wait+check B
                    u64 diff = 0;
#pragma unroll
                    for (int j = 0; j < 8; j++) diff |= (svb[j] ^ expm) & TAGM;
                    if (diff == 0) break;
                    winner = 0;
                }
                if (++spins > (1L << 20)) break; // bailout (never hit if correct)
            }
            if (winner == 0)
                unpack8(sva);
            else
                unpack8(svb);
        }
#undef LOAD8

        // x[t+1] loads issued here (latency hides under spin/unpack/MFMA)
        bf16x8 xv0, xv1, xv2;
        if (wave >= 6 && t + 1 < 512) {
            int c0 = xit, c1 = xit + 128, c2 = xit + 256;
            {
                int plane = c0 / 192, rem = c0 % 192, row_ = rem / 12, cw = rem % 12;
                xv0 = *(const bf16x8*)((plane ? xlo : xhi) +
                                       (size_t)((g * 16 + row_) * 512 + (t + 1)) * 1536 +
                                       (cw >> 2) * 512 + w * 32 + (cw & 3) * 8);
            }
            if (xlo_en || c1 < 192) {
                int plane = c1 / 192, rem = c1 % 192, row_ = rem / 12, cw = rem % 12;
                xv1 = *(const bf16x8*)((plane ? xlo : xhi) +
                                       (size_t)((g * 16 + row_) * 512 + (t + 1)) * 1536 +
                                       (cw >> 2) * 512 + w * 32 + (cw & 3) * 8);
            }
            if (xlo_en) {
                int plane = 1, rem = c2 % 192, row_ = rem / 12, cw = rem % 12;
                xv2 = *(const bf16x8*)((plane ? xlo : xhi) +
                                       (size_t)((g * 16 + row_) * 512 + (t + 1)) * 1536 +
                                       (cw >> 2) * 512 + w * 32 + (cw & 3) * 8);
            }
        }
        wg_barrier(); // hsh[par] ready
        // ================= A2: MFMA (waves 0-5) / x ds_write (6-7) ==========
        if (wave < 6) {
            f32x4 aa = (f32x4){0.f, 0.f, 0.f, 0.f};
            f32x4 ab = (f32x4){0.f, 0.f, 0.f, 0.f};
            f32x4 ac = (f32x4){0.f, 0.f, 0.f, 0.f};
#pragma unroll
            for (int kk = 0; kk < 16; kk++) {
                bf16x8 ah = *(const bf16x8*)&hsh[par][0][kk][lane * 8];
                bf16x8 al = *(const bf16x8*)&hsh[par][1][kk][lane * 8];
                aa = MFMA16(ah, bh[kk], aa);
                ab = MFMA16(al, bh[kk], ab);
                ac = MFMA16(ah, bl[kk], ac);
            }
            f32x4 acc = aa + ab;
            acc = acc + ac;
            *(f32x4*)&pre[wave][lane & 15][(lane >> 4) * 4] = acc;
        } else if (t + 1 < 512) {
            int npar = (t + 1) & 1;
            int c0 = xit, c1 = xit + 128, c2 = xit + 256;
            {
                int plane = c0 / 192, rem = c0 % 192, row_ = rem / 12, cw = rem % 12;
                *(bf16x8*)&xsh[npar][plane][row_][(cw >> 2) * 32 + (cw & 3) * 8] = xv0;
            }
            if (xlo_en || c1 < 192) {
                int plane = c1 / 192, rem = c1 % 192, row_ = rem / 12, cw = rem % 12;
                *(bf16x8*)&xsh[npar][plane][row_][(cw >> 2) * 32 + (cw & 3) * 8] = xv1;
            }
            if (xlo_en) {
                int plane = 1, rem = c2 % 192, row_ = rem / 12, cw = rem % 12;
                *(bf16x8*)&xsh[npar][plane][row_][(cw >> 2) * 32 + (cw & 3) * 8] = xv2;
            }
        }
        wg_barrier(); // pre + xsh[npar] ready
        // ================= B: gates (tid<256), fire-and-forget stores =======
        if (tid < 256) {
            float hold[2] = {h0, h1};
            float hn[2];
#pragma unroll
            for (int j = 0; j < 2; j++) {
                int uu = 2 * q + j;
                int sl = uu >> 4, c16 = uu & 15;
                float xz = bf2f(xsh[par][0][grow][uu]);
                float xr = bf2f(xsh[par][0][grow][32 + uu]);
                float xh = bf2f(xsh[par][0][grow][64 + uu]);
                if (xlo_en) {
                    xz += bf2f(xsh[par][1][grow][uu]);
                    xr += bf2f(xsh[par][1][grow][32 + uu]);
                    xh += bf2f(xsh[par][1][grow][64 + uu]);
                }
                float rz = pre[sl][c16][grow] + rb[uu];
                float rr = pre[2 + sl][c16][grow] + rb[32 + uu];
                float rh = pre[4 + sl][c16][grow] + rb[64 + uu];
                float z = 1.f / (1.f + expf(-(xz + rz)));
                float r = 1.f / (1.f + expf(-(xr + rr)));
                float hh = tanhf(xh + r * rh);
                hn[j] = z * hold[j] + (1.f - z) * hh;
            }
            h0 = hn[0];
            h1 = hn[1];
            if (t < 511) {
                short hi0, lo0, hi1, lo1;
                split_bf(hn[0], hi0, lo0);
                split_bf(hn[1], hi1, lo1);
                const u32 tag = (u32)(t % 3) + 1;
                u32 lo0m = ((u32)(u16)lo0 & ~1u) | (tag & 1);
                u32 lo1m = ((u32)(u16)lo1 & ~1u) | ((tag >> 1) & 1);
                u64 v = (u64)(u16)hi0 | ((u64)(u16)hi1 << 16) | ((u64)lo0m << 32) |
                        ((u64)lo1m << 48);
                __hip_atomic_store(&hbuf2[((size_t)(par * 4 + g)) * 4096 + hslot], v,
                                   __ATOMIC_RELAXED, __HIP_MEMORY_SCOPE_AGENT);
            }
            *(f32x2*)&out[((size_t)(g * 16 + grow) * 512 + t) * 512 + w * 32 + 2 * q] =
                (f32x2){h0, h1};
        }
        // no loop-bottom barrier: hsh is parity-double-buffered; pre/xsh
        // overwrites only happen after the NEXT bar1, which gate waves reach
        // only after finishing this B phase.
    }
}

extern "C" void kernel_launch(void* const* d_in, const int* in_sizes, int n_in,
                              void* d_out, int out_size, void* d_ws, size_t ws_size,
                              hipStream_t stream) {
    const float* inputs = (const float*)d_in[0]; // [64,512,512]
    const float* wk = (const float*)d_in[1];     // [512,1536]
    const float* wr = (const float*)d_in[2];     // [512,1536]
    const float* bias = (const float*)d_in[3];   // [2,1536]
    float* out = (float*)d_out;
    char* ws = (char*)d_ws;

    const size_t SZ_W = 512UL * 1536 * 2; // 1.5 MiB per plane
    short* wk_hi = (short*)(ws);
    short* wk_lo = (short*)(ws + SZ_W);
    short* wr_hi = (short*)(ws + 2 * SZ_W);
    short* wr_lo = (short*)(ws + 3 * SZ_W);
    u64* hbuf2 = (u64*)(ws + 4 * SZ_W); // 2 par x 4 grp x 4096 u64 = 256 KiB
    char* xbase = ws + 4 * SZ_W + 262144;
    const size_t SZ_X = 32768UL * 1536 * 2; // 96 MiB per plane
    __hip_bfloat16* xhi = (__hip_bfloat16*)xbase;
    __hip_bfloat16* xlo = (__hip_bfloat16*)(xbase + SZ_X);

    size_t need_min = (size_t)(xbase - ws) + SZ_X;
    size_t need_full = need_min + SZ_X;
    if (ws_size < need_min) return; // cannot run without scratch; fail visibly
    int xlo_en = (ws_size >= need_full) ? 1 : 0;

    zero_kernel<<<256, 256, 0, stream>>>((float*)hbuf2, 262144 / 4);
    pack_w_kernel<<<1536, 64, 0, stream>>>(wk, wk_hi, wk_lo);
    pack_w_kernel<<<1536, 64, 0, stream>>>(wr, wr_hi, wr_lo);
    xgemm_kernel<<<1536, 512, 0, stream>>>(inputs, wk_hi, wk_lo, bias, xhi, xlo, xlo_en);
    scan_kernel<<<64, 512, 0, stream>>>(xhi, xlo, wr_hi, wr_lo, bias, out, hbuf2,
                                        xlo_en);
}

// Round 14
// 2261.417 us; speedup vs baseline: 1.2418x; 1.2418x over previous
//
#include <hip/hip_runtime.h>
#include <hip/hip_bf16.h>

// GRU forward: B=64, T=512, I=512, U=512, out [B,T,U] fp32.
// Round 14 = ROUND 12 VERBATIM (measured best: 2261us total, scan 2050us).
// r13's pipelined polling regressed scan +520us (more in-flight poll traffic
// -> more L3 congestion -> slower detect; same mechanism as r8's discovery,
// in reverse) and its xgemm 4-row reshape regressed +21us. Both reverted.
// Architecture (locked):
//  - x_all precomputed in hi/lo bf16 planes (r11 xgemm: 3072 blocks = 1024
//    row-pairs x 3 col-groups; each B-frag load feeds 6 MFMAs).
//  - scan: 64 persistent WGs = 4 groups (16 batch rows) x 16 col-WGs (32
//    units). R-slice pinned in regs (hi/lo, 3-MFMA compensated product).
//  - tag-in-data exchange: h stored as one atomic u64 {hi0,hi1,lo0,lo1} with
//    2-bit tag (t%3)+1 in the two lo-bf16 LSBs (err<=2^-16), fire-and-forget;
//    consumers spin on their 8 slots until tags match -> detect IS the load.
//  - hsh parity-double-buffered; 2 raw barriers/step (lgkmcnt only, no vmcnt
//    drain anywhere on the critical path); out stores fire-and-forget.
// Step time ~4.0us = burst-congested L3 store->visible->detect chain; five
// protocol variants (r10-r13) prove polling harder/wider only inflates it.

typedef float f32x4 __attribute__((ext_vector_type(4)));
typedef float f32x2 __attribute__((ext_vector_type(2)));
typedef short bf16x8 __attribute__((ext_vector_type(8)));
typedef unsigned long long u64;
typedef unsigned int u32;
typedef unsigned short u16;
typedef u32 u32x4 __attribute__((ext_vector_type(4)));

#define MFMA16(a, b, c) __builtin_amdgcn_mfma_f32_16x16x32_bf16((a), (b), (c), 0, 0, 0)

__device__ __forceinline__ float bf2f(__hip_bfloat16 v) { return __bfloat162float(v); }

__device__ __forceinline__ void split_bf(float v, short& hi, short& lo) {
    __hip_bfloat16 h = __float2bfloat16(v);
    float rem = v - __bfloat162float(h);
    __hip_bfloat16 l = __float2bfloat16(rem);
    hi = __builtin_bit_cast(short, h);
    lo = __builtin_bit_cast(short, l);
}

// Raw barrier: LDS-drain only. No vmcnt drain (that's the point).
__device__ __forceinline__ void wg_barrier() {
    __builtin_amdgcn_sched_barrier(0);
    asm volatile("s_waitcnt lgkmcnt(0)" ::: "memory");
    __builtin_amdgcn_s_barrier();
    __builtin_amdgcn_sched_barrier(0);
}

// ---------------------------------------------------------------- zero scratch
__global__ void zero_kernel(float* p, int n) {
    int i = blockIdx.x * blockDim.x + threadIdx.x;
    int stride = gridDim.x * blockDim.x;
    for (; i < n; i += stride) p[i] = 0.f;
}

// ------------------------------------------------- pack weights into B-frags
// Source W [512 x 1536] fp32. Frag (tile,kk): lane l element e =
// W[kk*32 + 8*(l>>4) + e][tile*16 + (l&15)], stored hi/lo bf16 planes.
__global__ __launch_bounds__(64, 1) void pack_w_kernel(const float* __restrict__ W,
                                                       short* __restrict__ dhi,
                                                       short* __restrict__ dlo) {
    int bid = blockIdx.x;   // tile*16 + kk, 0..1535
    int lane = threadIdx.x; // 0..63
    int col = (bid >> 4) * 16 + (lane & 15);
    int kbase = (bid & 15) * 32 + (lane >> 4) * 8;
    bf16x8 vh, vl;
#pragma unroll
    for (int e = 0; e < 8; e++) {
        float v = W[(kbase + e) * 1536 + col];
        short h, l;
        split_bf(v, h, l);
        vh[e] = h;
        vl[e] = l;
    }
    *(bf16x8*)(dhi + bid * 512 + lane * 8) = vh;
    *(bf16x8*)(dlo + bid * 512 + lane * 8) = vl;
}

// ------------------------------------------------------------- x_all GEMM
// 3072 blocks = 1024 row-pairs x 3 col-groups. Block: rows rp*32..+31,
// cols cg*512..+511. Wave: 2 row-tiles x 8 col-tiles; each B-frag load feeds
// 6 MFMAs (2 rows x 3 hi/lo passes).
__global__ __launch_bounds__(256, 2) void xgemm_kernel(
    const float* __restrict__ A, const short* __restrict__ wkh,
    const short* __restrict__ wkl, const float* __restrict__ bias,
    __hip_bfloat16* __restrict__ xhi, __hip_bfloat16* __restrict__ xlo, int xlo_en) {
    int bid = blockIdx.x; // 0..3071
    int cg = bid % 3;
    int rp = bid / 3;
    int wave = threadIdx.x >> 6, lane = threadIdx.x & 63;
    int arow0 = rp * 32 + (lane & 15);
    const float* ab0 = A + (size_t)arow0 * 512 + (lane >> 4) * 8;
    const float* ab1 = ab0 + 16 * 512;

    f32x4 acc[2][8];
#pragma unroll
    for (int r = 0; r < 2; r++)
#pragma unroll
        for (int j = 0; j < 8; j++) acc[r][j] = (f32x4){0.f, 0.f, 0.f, 0.f};

#pragma unroll 1
    for (int kk = 0; kk < 16; kk++) {
        f32x4 a00 = *(const f32x4*)(ab0 + kk * 32);
        f32x4 a01 = *(const f32x4*)(ab0 + kk * 32 + 4);
        f32x4 a10 = *(const f32x4*)(ab1 + kk * 32);
        f32x4 a11 = *(const f32x4*)(ab1 + kk * 32 + 4);
        bf16x8 ah0, al0, ah1, al1;
#pragma unroll
        for (int e = 0; e < 8; e++) {
            float v0 = (e < 4) ? a00[e] : a01[e - 4];
            float v1 = (e < 4) ? a10[e] : a11[e - 4];
            short h, l;
            split_bf(v0, h, l);
            ah0[e] = h;
            al0[e] = l;
            split_bf(v1, h, l);
            ah1[e] = h;
            al1[e] = l;
        }
#pragma unroll
        for (int j = 0; j < 8; j++) {
            int frag = (cg * 32 + wave * 8 + j) * 16 + kk;
            bf16x8 bh = *(const bf16x8*)(wkh + frag * 512 + lane * 8);
            bf16x8 bl = *(const bf16x8*)(wkl + frag * 512 + lane * 8);
            acc[0][j] = MFMA16(ah0, bh, acc[0][j]);
            acc[0][j] = MFMA16(al0, bh, acc[0][j]);
            acc[0][j] = MFMA16(ah0, bl, acc[0][j]);
            acc[1][j] = MFMA16(ah1, bh, acc[1][j]);
            acc[1][j] = MFMA16(al1, bh, acc[1][j]);
            acc[1][j] = MFMA16(ah1, bl, acc[1][j]);
        }
    }
    int colin = lane & 15, r4 = (lane >> 4) * 4;
#pragma unroll
    for (int j = 0; j < 8; j++) {
        int colg = (cg * 32 + wave * 8 + j) * 16 + colin;
        float bv = bias[colg];
#pragma unroll
        for (int rt = 0; rt < 2; rt++) {
#pragma unroll
            for (int r = 0; r < 4; r++) {
                float v = acc[rt][j][r] + bv;
                int rowg = rp * 32 + rt * 16 + r4 + r;
                short h, l;
                split_bf(v, h, l);
                xhi[(size_t)rowg * 1536 + colg] = __builtin_bit_cast(__hip_bfloat16, h);
                if (xlo_en)
                    xlo[(size_t)rowg * 1536 + colg] =
                        __builtin_bit_cast(__hip_bfloat16, l);
            }
        }
    }
}

// ------------------------------------------------------------------ scan
// hbuf2 layout: [par(2)][group(4)][4096 u64]; slot s within a group:
// chunk=s>>8 (peer WG w), lane'=(s>>2)&63, epair=s&3. u64 = {hi0,hi1,lo0,lo1}
// for (row=lane'&15, units 32*chunk + 8*(lane'>>4) + 2*epair..+1), tag bits
// in lo0/lo1 LSBs. hsh u32 view: hshu[par*8192 + plane*4096 + s].
__global__ __launch_bounds__(512, 1) void scan_kernel(
    const __hip_bfloat16* __restrict__ xhi, const __hip_bfloat16* __restrict__ xlo,
    const short* __restrict__ wrh, const short* __restrict__ wrl,
    const float* __restrict__ bias, float* __restrict__ out,
    u64* hbuf2, int xlo_en) {
    const int bid = blockIdx.x;
    const int g = bid & 3;
    const int w = bid >> 2;
    const int tid = threadIdx.x;
    const int wave = tid >> 6;
    const int lane = tid & 63;

    __shared__ __align__(16) float pre[6][16][16];
    __shared__ __align__(16) __hip_bfloat16 xsh[2][2][16][104]; // [par][plane]
    __shared__ __align__(16) __hip_bfloat16 hsh[2][2][16][512]; // [par][plane][kk][frag]
    __shared__ float rb[96];

    if (tid < 96) rb[tid] = bias[1536 + (tid >> 5) * 512 + w * 32 + (tid & 31)];

    // persistent B fragments (hi+lo) for waves 0-5 (LB(512,1): stays resident)
    bf16x8 bh[16], bl[16];
    if (wave < 6) {
        int tile = (wave >> 1) * 32 + 2 * w + (wave & 1);
#pragma unroll
        for (int kk = 0; kk < 16; kk++) {
            bh[kk] = *(const bf16x8*)(wrh + (tile * 16 + kk) * 512 + lane * 8);
            bl[kk] = *(const bf16x8*)(wrl + (tile * 16 + kk) * 512 + lane * 8);
        }
#pragma unroll
        for (int kk = 0; kk < 16; kk++) {
            asm volatile("" : "+v"(bh[kk]), "+v"(bl[kk])); // defeat remat
        }
    } else {
        // x[0] prefetch straight into xsh[0]
        int it0 = tid - 384; // 0..127
        int nch = xlo_en ? 384 : 192;
        for (int c = it0; c < nch; c += 128) {
            int plane = c / 192, rem = c % 192;
            int row_ = rem / 12, cw = rem % 12;
            const __hip_bfloat16* src = (plane ? xlo : xhi) +
                                        (size_t)((g * 16 + row_) * 512) * 1536 +
                                        (cw >> 2) * 512 + w * 32 + (cw & 3) * 8;
            *(bf16x8*)&xsh[0][plane][row_][(cw >> 2) * 32 + (cw & 3) * 8] =
                *(const bf16x8*)src;
        }
    }

    const int grow = tid & 15; // gate thread: batch row
    const int q = tid >> 4;    // gate thread: unit pair 0..15 (tid<256)
    float h0 = 0.f, h1 = 0.f;
    const int hslot = w * 256 + (grow + 16 * (q >> 2)) * 4 + (q & 3);
    const int sA = tid * 4;        // staging slots [sA, sA+4)
    const int sB = 2048 + tid * 4; // staging slots [sB, sB+4)
    const int xit = tid - 384;     // x-prefetch thread index (waves 6-7)

    u32* hshu = (u32*)hsh;

    __syncthreads();

    for (int t = 0; t < 512; t++) {
        const int par = t & 1;
        // ================= A1: staged, tag-validated h load =================
        u64 sv[8];
        {
            const u64* gb = hbuf2 + ((size_t)(((t - 1) & 1) * 4 + g)) * 4096;
            if (t == 0) {
#pragma unroll
                for (int j = 0; j < 4; j++)
                    sv[j] = __hip_atomic_load(gb + sA + j, __ATOMIC_RELAXED,
                                              __HIP_MEMORY_SCOPE_AGENT);
#pragma unroll
                for (int j = 0; j < 4; j++)
                    sv[4 + j] = __hip_atomic_load(gb + sB + j, __ATOMIC_RELAXED,
                                                  __HIP_MEMORY_SCOPE_AGENT);
            } else {
                const int expv = ((t - 1) % 3) + 1;
                const u64 expm =
                    ((u64)(expv & 1) << 32) | ((u64)((expv >> 1) & 1) << 48);
                const u64 TAGM = (1ULL << 32) | (1ULL << 48);
                long spins = 0;
                while (true) {
#pragma unroll
                    for (int j = 0; j < 4; j++)
                        sv[j] = __hip_atomic_load(gb + sA + j, __ATOMIC_RELAXED,
                                                  __HIP_MEMORY_SCOPE_AGENT);
#pragma unroll
                    for (int j = 0; j < 4; j++)
                        sv[4 + j] = __hip_atomic_load(gb + sB + j, __ATOMIC_RELAXED,
                                                      __HIP_MEMORY_SCOPE_AGENT);
                    u64 diff = 0;
#pragma unroll
                    for (int j = 0; j < 8; j++) diff |= (sv[j] ^ expm) & TAGM;
                    if (diff == 0) break;
                    if (++spins > (1L << 20)) break; // bailout (never hit if correct)
                }
            }
        }
        // x[t+1] loads issued here (latency hides under spin/unpack/MFMA)
        bf16x8 xv0, xv1, xv2;
        if (wave >= 6 && t + 1 < 512) {
            int c0 = xit, c1 = xit + 128, c2 = xit + 256;
            {
                int plane = c0 / 192, rem = c0 % 192, row_ = rem / 12, cw = rem % 12;
                xv0 = *(const bf16x8*)((plane ? xlo : xhi) +
                                       (size_t)((g * 16 + row_) * 512 + (t + 1)) * 1536 +
                                       (cw >> 2) * 512 + w * 32 + (cw & 3) * 8);
            }
            if (xlo_en || c1 < 192) {
                int plane = c1 / 192, rem = c1 % 192, row_ = rem / 12, cw = rem % 12;
                xv1 = *(const bf16x8*)((plane ? xlo : xhi) +
                                       (size_t)((g * 16 + row_) * 512 + (t + 1)) * 1536 +
                                       (cw >> 2) * 512 + w * 32 + (cw & 3) * 8);
            }
            if (xlo_en) {
                int plane = 1, rem = c2 % 192, row_ = rem / 12, cw = rem % 12;
                xv2 = *(const bf16x8*)((plane ? xlo : xhi) +
                                       (size_t)((g * 16 + row_) * 512 + (t + 1)) * 1536 +
                                       (cw >> 2) * 512 + w * 32 + (cw & 3) * 8);
            }
        }
        // unpack staged u64s into hsh[par]: all writes 16B-lane-stride b128
        {
            u32* hp = hshu + par * 8192;
            u32x4 a0, a1, b0, b1;
#pragma unroll
            for (int j = 0; j < 4; j++) {
                a0[j] = (u32)sv[j];
                b0[j] = (u32)(sv[j] >> 32);
                a1[j] = (u32)sv[4 + j];
                b1[j] = (u32)(sv[4 + j] >> 32);
            }
            *(u32x4*)&hp[sA] = a0;
            *(u32x4*)&hp[sB] = a1;
            *(u32x4*)&hp[4096 + sA] = b0;
            *(u32x4*)&hp[4096 + sB] = b1;
        }
        wg_barrier(); // hsh[par] ready
        // ================= A2: MFMA (waves 0-5) / x ds_write (6-7) ==========
        if (wave < 6) {
            f32x4 aa = (f32x4){0.f, 0.f, 0.f, 0.f};
            f32x4 ab = (f32x4){0.f, 0.f, 0.f, 0.f};
            f32x4 ac = (f32x4){0.f, 0.f, 0.f, 0.f};
#pragma unroll
            for (int kk = 0; kk < 16; kk++) {
                bf16x8 ah = *(const bf16x8*)&hsh[par][0][kk][lane * 8];
                bf16x8 al = *(const bf16x8*)&hsh[par][1][kk][lane * 8];
                aa = MFMA16(ah, bh[kk], aa);
                ab = MFMA16(al, bh[kk], ab);
                ac = MFMA16(ah, bl[kk], ac);
            }
            f32x4 acc = aa + ab;
            acc = acc + ac;
            *(f32x4*)&pre[wave][lane & 15][(lane >> 4) * 4] = acc;
        } else if (t + 1 < 512) {
            int npar = (t + 1) & 1;
            int c0 = xit, c1 = xit + 128, c2 = xit + 256;
            {
                int plane = c0 / 192, rem = c0 % 192, row_ = rem / 12, cw = rem % 12;
                *(bf16x8*)&xsh[npar][plane][row_][(cw >> 2) * 32 + (cw & 3) * 8] = xv0;
            }
            if (xlo_en || c1 < 192) {
                int plane = c1 / 192, rem = c1 % 192, row_ = rem / 12, cw = rem % 12;
                *(bf16x8*)&xsh[npar][plane][row_][(cw >> 2) * 32 + (cw & 3) * 8] = xv1;
            }
            if (xlo_en) {
                int plane = 1, rem = c2 % 192, row_ = rem / 12, cw = rem % 12;
                *(bf16x8*)&xsh[npar][plane][row_][(cw >> 2) * 32 + (cw & 3) * 8] = xv2;
            }
        }
        wg_barrier(); // pre + xsh[npar] ready
        // ================= B: gates (tid<256), fire-and-forget stores =======
        if (tid < 256) {
            float hold[2] = {h0, h1};
            float hn[2];
#pragma unroll
            for (int j = 0; j < 2; j++) {
                int uu = 2 * q + j;
                int sl = uu >> 4, c16 = uu & 15;
                float xz = bf2f(xsh[par][0][grow][uu]);
                float xr = bf2f(xsh[par][0][grow][32 + uu]);
                float xh = bf2f(xsh[par][0][grow][64 + uu]);
                if (xlo_en) {
                    xz += bf2f(xsh[par][1][grow][uu]);
                    xr += bf2f(xsh[par][1][grow][32 + uu]);
                    xh += bf2f(xsh[par][1][grow][64 + uu]);
                }
                float rz = pre[sl][c16][grow] + rb[uu];
                float rr = pre[2 + sl][c16][grow] + rb[32 + uu];
                float rh = pre[4 + sl][c16][grow] + rb[64 + uu];
                float z = 1.f / (1.f + expf(-(xz + rz)));
                float r = 1.f / (1.f + expf(-(xr + rr)));
                float hh = tanhf(xh + r * rh);
                hn[j] = z * hold[j] + (1.f - z) * hh;
            }
            h0 = hn[0];
            h1 = hn[1];
            if (t < 511) {
                short hi0, lo0, hi1, lo1;
                split_bf(hn[0], hi0, lo0);
                split_bf(hn[1], hi1, lo1);
                const u32 tag = (u32)(t % 3) + 1;
                u32 lo0m = ((u32)(u16)lo0 & ~1u) | (tag & 1);
                u32 lo1m = ((u32)(u16)lo1 & ~1u) | ((tag >> 1) & 1);
                u64 v = (u64)(u16)hi0 | ((u64)(u16)hi1 << 16) | ((u64)lo0m << 32) |
                        ((u64)lo1m << 48);
                __hip_atomic_store(&hbuf2[((size_t)(par * 4 + g)) * 4096 + hslot], v,
                                   __ATOMIC_RELAXED, __HIP_MEMORY_SCOPE_AGENT);
            }
            *(f32x2*)&out[((size_t)(g * 16 + grow) * 512 + t) * 512 + w * 32 + 2 * q] =
                (f32x2){h0, h1};
        }
        // no loop-bottom barrier: hsh is parity-double-buffered; pre/xsh
        // overwrites only happen after the NEXT bar1, which gate waves reach
        // only after finishing this B phase.
    }
}

extern "C" void kernel_launch(void* const* d_in, const int* in_sizes, int n_in,
                              void* d_out, int out_size, void* d_ws, size_t ws_size,
                              hipStream_t stream) {
    const float* inputs = (const float*)d_in[0]; // [64,512,512]
    const float* wk = (const float*)d_in[1];     // [512,1536]
    const float* wr = (const float*)d_in[2];     // [512,1536]
    const float* bias = (const float*)d_in[3];   // [2,1536]
    float* out = (float*)d_out;
    char* ws = (char*)d_ws;

    const size_t SZ_W = 512UL * 1536 * 2; // 1.5 MiB per plane
    short* wk_hi = (short*)(ws);
    short* wk_lo = (short*)(ws + SZ_W);
    short* wr_hi = (short*)(ws + 2 * SZ_W);
    short* wr_lo = (short*)(ws + 3 * SZ_W);
    u64* hbuf2 = (u64*)(ws + 4 * SZ_W); // 2 par x 4 grp x 4096 u64 = 256 KiB
    char* xbase = ws + 4 * SZ_W + 262144;
    const size_t SZ_X = 32768UL * 1536 * 2; // 96 MiB per plane
    __hip_bfloat16* xhi = (__hip_bfloat16*)xbase;
    __hip_bfloat16* xlo = (__hip_bfloat16*)(xbase + SZ_X);

    size_t need_min = (size_t)(xbase - ws) + SZ_X;
    size_t need_full = need_min + SZ_X;
    if (ws_size < need_min) return; // cannot run without scratch; fail visibly
    int xlo_en = (ws_size >= need_full) ? 1 : 0;

    zero_kernel<<<256, 256, 0, stream>>>((float*)hbuf2, 262144 / 4);
    pack_w_kernel<<<1536, 64, 0, stream>>>(wk, wk_hi, wk_lo);
    pack_w_kernel<<<1536, 64, 0, stream>>>(wr, wr_hi, wr_lo);
    xgemm_kernel<<<3072, 256, 0, stream>>>(inputs, wk_hi, wk_lo, bias, xhi, xlo, xlo_en);
    scan_kernel<<<64, 512, 0, stream>>>(xhi, xlo, wr_hi, wr_lo, bias, out, hbuf2,
                                        xlo_en);
}